// Round 6
// baseline (708.555 us; speedup 1.0000x reference)
//
#include <hip/hip_runtime.h>

#define B_SZ 2
#define T_SZ 4096
#define H_N  8

typedef unsigned short u16;
typedef __attribute__((ext_vector_type(8))) short short8;
typedef __attribute__((ext_vector_type(4))) float f32x4;
typedef __attribute__((ext_vector_type(4))) unsigned short u16x4;

__device__ __forceinline__ u16 f2bf(float f) {            // round-to-nearest-even
    unsigned int u;
    __builtin_memcpy(&u, &f, 4);
    u = (u + 0x7fffu + ((u >> 16) & 1u)) >> 16;
    return (u16)u;
}
__device__ __forceinline__ u16 f2bf_up(float f) {         // round-half-up (p >= 0 only)
    unsigned int u;
    __builtin_memcpy(&u, &f, 4);
    return (u16)((u + 0x8000u) >> 16);
}
__device__ __forceinline__ f32x4 mfma16(short8 a, short8 b, f32x4 c) {
    return __builtin_amdgcn_mfma_f32_16x16x32_bf16(a, b, c, 0, 0, 0);
}

// ---------- f32 -> bf16 elementwise, 4 elems/thread ----------
__global__ void k_cvt(const float* __restrict__ src, u16* __restrict__ dst) {
    int i = (blockIdx.x * 256 + threadIdx.x) * 4;
    float4 v = *(const float4*)(src + i);
    u16x4 o = { f2bf(v.x), f2bf(v.y), f2bf(v.z), f2bf(v.w) };
    *(u16x4*)(dst + i) = o;
}

// ---------- f32 [K][N] -> bf16 [N][K] (convert + transpose) ----------
__global__ void k_cvt_t(const float* __restrict__ src, u16* __restrict__ dst, int K, int N) {
    int idx = blockIdx.x * 256 + threadIdx.x;
    int k = idx / N, n = idx - k * N;
    dst[(size_t)n * K + k] = f2bf(src[idx]);
}

// ---------- GEMM: C[M,N] = A[M,512] x Bt[N,512]^T (+ optional f32 bias[N]) ----------
template <typename OutT>
__global__ __launch_bounds__(256) void k_gemm(const u16* __restrict__ A, const u16* __restrict__ Bt,
                                              const float* __restrict__ bias, OutT* __restrict__ C,
                                              int M, int N) {
    const int K = 512;
    int m0 = blockIdx.x * 64;
    int tid = threadIdx.x;
    int wave = tid >> 6, lane = tid & 63, l16 = lane & 15, quad = lane >> 4;
    int ncol = blockIdx.y * 64 + wave * 16 + l16;

    f32x4 acc[4];
#pragma unroll
    for (int i = 0; i < 4; ++i) acc[i] = (f32x4){0.f, 0.f, 0.f, 0.f};

    const u16* bp = Bt + (size_t)ncol * K + quad * 8;
    const u16* ap = A + (size_t)(m0 + l16) * K + quad * 8;

    for (int k0 = 0; k0 < K; k0 += 32) {
        short8 bfr = *(const short8*)(bp + k0);
#pragma unroll
        for (int i = 0; i < 4; ++i) {
            short8 afr = *(const short8*)(ap + (size_t)(i * 16) * K + k0);
            acc[i] = mfma16(afr, bfr, acc[i]);
        }
    }

    float bb = bias ? bias[ncol] : 0.f;
#pragma unroll
    for (int i = 0; i < 4; ++i)
#pragma unroll
        for (int r = 0; r < 4; ++r) {
            int row = m0 + i * 16 + quad * 4 + r;
            float val = acc[i][r] + bb;
            if constexpr (__is_same(OutT, float)) {
                C[(size_t)row * N + ncol] = val;
            } else {
                C[(size_t)row * N + ncol] = f2bf(val);
            }
        }
}

// ---------- flash attention: split-K in block + software-pipelined loads ----------
// grid (T/64, H, B); block 512 = 8 waves. Wave w: q-rows (w&3)*16..+15,
// keys (w>>2)*2048..+2047 (64 iters of 32 keys). Partials combine additively
// (no-max softmax => same implicit base), one LDS exchange + barrier at end.
// S^T trick (round 5): A=K with row perm pi0(m)=(m>>2)*8+(m&3), pi1=pi0+4 ->
// lane (l16,q) holds P[qrow=l16][keys q*8..q*8+7] == PV B-frag. PV: A=V^T -> O^T.
// Pipeline: prefetch next iter's K before consuming current; V issued at iter top.
__global__ __launch_bounds__(512) void k_flash(const u16* __restrict__ qk, const u16* __restrict__ vt,
                                               u16* __restrict__ o) {
    const float CEXP = 0.51006973f; // (8^-0.5) * log2(e)
    int qt = blockIdx.x, h = blockIdx.y, b = blockIdx.z;
    int tid = threadIdx.x;
    int wave = tid >> 6, lane = tid & 63, l16 = lane & 15, q = lane >> 4;
    int qw = wave & 3;                    // q-row group
    int ksplit = (wave >> 2) * 2048;      // key half

    __shared__ float red[4][64][17];      // partner partial O^T (16) + l (1); 17 floats -> conflict-free

    const u16* qrow = qk + (size_t)(b * T_SZ + qt * 64 + qw * 16 + l16) * 1024 + h * 64 + q * 8;
    short8 qf0 = *(const short8*)(qrow);
    short8 qf1 = *(const short8*)(qrow + 32);

    const u16* kbase = qk + (size_t)b * T_SZ * 1024 + 512 + h * 64;
    const u16* vbase = vt + (size_t)(h * 64) * 8192 + (size_t)b * T_SZ + ksplit;

    int pi0 = (l16 >> 2) * 8 + (l16 & 3);
    const u16* kp0 = kbase + (size_t)(ksplit + pi0) * 1024 + q * 8;   // +4 key rows = +4096 u16

    f32x4 oacc[4];
#pragma unroll
    for (int c = 0; c < 4; ++c) oacc[c] = (f32x4){0.f, 0.f, 0.f, 0.f};
    float l_acc = 0.f;

    // pipeline prologue: K for iter 0
    short8 c00 = *(const short8*)(kp0);
    short8 c01 = *(const short8*)(kp0 + 32);
    short8 c10 = *(const short8*)(kp0 + 4096);
    short8 c11 = *(const short8*)(kp0 + 4096 + 32);

    for (int kk = 0; kk < 2048; kk += 32) {
        // V loads for THIS iter (latency covered by S-MFMA + softmax below)
        short8 vf0 = *(const short8*)(vbase + (size_t)(0 * 16 + l16) * 8192 + kk + q * 8);
        short8 vf1 = *(const short8*)(vbase + (size_t)(1 * 16 + l16) * 8192 + kk + q * 8);
        short8 vf2 = *(const short8*)(vbase + (size_t)(2 * 16 + l16) * 8192 + kk + q * 8);
        short8 vf3 = *(const short8*)(vbase + (size_t)(3 * 16 + l16) * 8192 + kk + q * 8);
        // prefetch NEXT iter's K (last iter prefetches harmless in-bounds garbage, never consumed)
        const u16* np = kp0 + (size_t)(kk + 32) * 1024;
        short8 n00 = *(const short8*)(np);
        short8 n01 = *(const short8*)(np + 32);
        short8 n10 = *(const short8*)(np + 4096);
        short8 n11 = *(const short8*)(np + 4096 + 32);

        f32x4 s0 = (f32x4){0.f, 0.f, 0.f, 0.f};
        f32x4 s1 = (f32x4){0.f, 0.f, 0.f, 0.f};
        s0 = mfma16(c00, qf0, s0); s0 = mfma16(c01, qf1, s0);  // S^T keys q*8+r
        s1 = mfma16(c10, qf0, s1); s1 = mfma16(c11, qf1, s1);  // S^T keys q*8+4+r

        short8 pf;
        float ls = 0.f;
#pragma unroll
        for (int r = 0; r < 4; ++r) {
            float p0 = exp2f(s0[r] * CEXP);
            float p1 = exp2f(s1[r] * CEXP);
            ls += p0 + p1;
            pf[r]     = (short)f2bf_up(p0);
            pf[4 + r] = (short)f2bf_up(p1);
        }
        l_acc += ls;

        oacc[0] = mfma16(vf0, pf, oacc[0]);   // O^T[d=c*16+q*4+r][qrow=l16]
        oacc[1] = mfma16(vf1, pf, oacc[1]);
        oacc[2] = mfma16(vf2, pf, oacc[2]);
        oacc[3] = mfma16(vf3, pf, oacc[3]);

        c00 = n00; c01 = n01; c10 = n10; c11 = n11;
    }

    // combine split-K partners: additive (shared implicit softmax base)
    if (wave >= 4) {
        float* rp = &red[qw][lane][0];
#pragma unroll
        for (int c = 0; c < 4; ++c)
#pragma unroll
            for (int r = 0; r < 4; ++r) rp[c * 4 + r] = oacc[c][r];
        rp[16] = l_acc;
    }
    __syncthreads();
    if (wave < 4) {
        const float* rp = &red[wave][lane][0];
#pragma unroll
        for (int c = 0; c < 4; ++c)
#pragma unroll
            for (int r = 0; r < 4; ++r) oacc[c][r] += rp[c * 4 + r];
        l_acc += rp[16];
        l_acc += __shfl_xor(l_acc, 16);   // sum the 4 quads of this qrow
        l_acc += __shfl_xor(l_acc, 32);
        float inv = 1.f / l_acc;

        u16* ob = o + (size_t)(b * T_SZ + qt * 64 + qw * 16 + l16) * 512 + h * 64 + q * 4;
#pragma unroll
        for (int c = 0; c < 4; ++c) {
            u16x4 w = { f2bf(oacc[c][0] * inv), f2bf(oacc[c][1] * inv),
                        f2bf(oacc[c][2] * inv), f2bf(oacc[c][3] * inv) };
            *(u16x4*)(ob + c * 16) = w;
        }
    }
}

extern "C" void kernel_launch(void* const* d_in, const int* in_sizes, int n_in,
                              void* d_out, int out_size, void* d_ws, size_t ws_size,
                              hipStream_t stream) {
    const float* x    = (const float*)d_in[0];   // [2,4096,512] f32
    const float* cond = (const float*)d_in[1];   // [2,4096,512] f32
    const float* Wqk  = (const float*)d_in[2];   // [512,1024]   f32
    const float* Wv   = (const float*)d_in[3];   // [512,512]    f32
    const float* Wu   = (const float*)d_in[4];   // [512,512]    f32
    const float* bu   = (const float*)d_in[5];   // [512]        f32
    float* out = (float*)d_out;                  // [2,4096,512] f32

    const size_t MT = (size_t)B_SZ * T_SZ;       // 8192
    u16* xb    = (u16*)d_ws;                     // [8192,512]   8 MB
    u16* cb    = xb + MT * 512;                  // [8192,512]   8 MB
    u16* qk_ws = cb + MT * 512;                  // [8192,1024] 16 MB
    u16* vt_ws = qk_ws + MT * 1024;              // [512,8192]   8 MB  (V^T)
    u16* at_ws = vt_ws + MT * 512;               // [8192,512]   8 MB
    u16* Wqk_t = at_ws + MT * 512;               // [1024,512]   1 MB
    u16* Wv_t  = Wqk_t + (size_t)1024 * 512;     // [512,512]  0.5 MB
    u16* Wu_t  = Wv_t + (size_t)512 * 512;       // [512,512]  0.5 MB

    k_cvt<<<(int)(MT * 512 / 1024), 256, 0, stream>>>(x, xb);
    k_cvt<<<(int)(MT * 512 / 1024), 256, 0, stream>>>(cond, cb);
    k_cvt_t<<<(512 * 1024) / 256, 256, 0, stream>>>(Wqk, Wqk_t, 512, 1024);
    k_cvt_t<<<(512 * 512) / 256, 256, 0, stream>>>(Wv, Wv_t, 512, 512);
    k_cvt_t<<<(512 * 512) / 256, 256, 0, stream>>>(Wu, Wu_t, 512, 512);

    k_gemm<u16><<<dim3(128, 16), 256, 0, stream>>>(cb, Wqk_t, nullptr, qk_ws, 8192, 1024);
    // V^T = Wv_t @ x^T : C[512 ch, 8192 tok] row-major -> vt[ch][b*4096+t]
    k_gemm<u16><<<dim3(8, 128), 256, 0, stream>>>(Wv_t, xb, nullptr, vt_ws, 512, 8192);
    k_flash<<<dim3(64, 8, 2), 512, 0, stream>>>(qk_ws, vt_ws, at_ws);
    k_gemm<float><<<dim3(128, 8), 256, 0, stream>>>(at_ws, Wu_t, bu, out, 8192, 512);
}

// Round 7
// 379.307 us; speedup vs baseline: 1.8680x; 1.8680x over previous
//
#include <hip/hip_runtime.h>

#define B_SZ 2
#define T_SZ 4096
#define H_N  8

typedef unsigned short u16;
typedef __attribute__((ext_vector_type(8))) short short8;
typedef __attribute__((ext_vector_type(4))) float f32x4;
typedef __attribute__((ext_vector_type(4))) unsigned short u16x4;

__device__ __forceinline__ u16 f2bf(float f) {            // round-to-nearest-even
    unsigned int u;
    __builtin_memcpy(&u, &f, 4);
    u = (u + 0x7fffu + ((u >> 16) & 1u)) >> 16;
    return (u16)u;
}
__device__ __forceinline__ u16 f2bf_up(float f) {         // round-half-up (p >= 0 only)
    unsigned int u;
    __builtin_memcpy(&u, &f, 4);
    return (u16)((u + 0x8000u) >> 16);
}
__device__ __forceinline__ f32x4 mfma16(short8 a, short8 b, f32x4 c) {
    return __builtin_amdgcn_mfma_f32_16x16x32_bf16(a, b, c, 0, 0, 0);
}

// ---------- f32 -> bf16 elementwise, 4 elems/thread ----------
__global__ void k_cvt(const float* __restrict__ src, u16* __restrict__ dst) {
    int i = (blockIdx.x * 256 + threadIdx.x) * 4;
    float4 v = *(const float4*)(src + i);
    u16x4 o = { f2bf(v.x), f2bf(v.y), f2bf(v.z), f2bf(v.w) };
    *(u16x4*)(dst + i) = o;
}

// ---------- f32 [K][N] -> bf16 [N][K] (convert + transpose) ----------
__global__ void k_cvt_t(const float* __restrict__ src, u16* __restrict__ dst, int K, int N) {
    int idx = blockIdx.x * 256 + threadIdx.x;
    int k = idx / N, n = idx - k * N;
    dst[(size_t)n * K + k] = f2bf(src[idx]);
}

// ---------- GEMM: C[M,N] = A[M,512] x Bt[N,512]^T (+ optional f32 bias[N]) ----------
// MODE 0: plain row-major C[row*N+ncol].
// MODE 1 (qk proj, N=1024): ncol<512 -> Qh[b,h,t,64] at C; ncol>=512 -> Kh[b,h,t,64] at C2.
// MODE 2 (v proj, M=512,N=8192): row=ch, ncol=tok -> Vb[b,h,kt,d,64k] blocked.
template <typename OutT, int MODE>
__global__ __launch_bounds__(256) void k_gemm(const u16* __restrict__ A, const u16* __restrict__ Bt,
                                              const float* __restrict__ bias, OutT* __restrict__ C,
                                              OutT* __restrict__ C2, int M, int N) {
    const int K = 512;
    int m0 = blockIdx.x * 64;
    int tid = threadIdx.x;
    int wave = tid >> 6, lane = tid & 63, l16 = lane & 15, quad = lane >> 4;
    int ncol = blockIdx.y * 64 + wave * 16 + l16;

    f32x4 acc[4];
#pragma unroll
    for (int i = 0; i < 4; ++i) acc[i] = (f32x4){0.f, 0.f, 0.f, 0.f};

    const u16* bp = Bt + (size_t)ncol * K + quad * 8;
    const u16* ap = A + (size_t)(m0 + l16) * K + quad * 8;

    for (int k0 = 0; k0 < K; k0 += 32) {
        short8 bfr = *(const short8*)(bp + k0);
#pragma unroll
        for (int i = 0; i < 4; ++i) {
            short8 afr = *(const short8*)(ap + (size_t)(i * 16) * K + k0);
            acc[i] = mfma16(afr, bfr, acc[i]);
        }
    }

    float bb = bias ? bias[ncol] : 0.f;
#pragma unroll
    for (int i = 0; i < 4; ++i)
#pragma unroll
        for (int r = 0; r < 4; ++r) {
            int row = m0 + i * 16 + quad * 4 + r;
            float val = acc[i][r] + bb;
            if constexpr (MODE == 0) {
                if constexpr (__is_same(OutT, float)) C[(size_t)row * N + ncol] = val;
                else                                  C[(size_t)row * N + ncol] = f2bf(val);
            } else if constexpr (MODE == 1) {
                int b = row >> 12, t = row & 4095, h = (ncol & 511) >> 6, d = ncol & 63;
                size_t addr = ((size_t)((b * 8 + h) * 4096 + t)) * 64 + d;
                (ncol < 512 ? C : C2)[addr] = f2bf(val);
            } else { // MODE 2
                int h = row >> 6, d = row & 63, b = ncol >> 12, t = ncol & 4095;
                int kt = t >> 6, k64 = t & 63;
                size_t addr = ((((size_t)(b * 8 + h) * 64 + kt) * 64 + d) << 6) + k64;
                C[addr] = f2bf(val);
            }
        }
}

// ---------- flash attention: LDS-tiled (m97 structure) + register S^T trick ----------
// grid (T/64, H, B); block 256 = 4 waves; wave owns 16 q rows. 64-key LDS tiles.
// Qh/Kh: [b,h,t,64] head-major (tile = contiguous 8KB). Vb: [b,h,kt,64d,64k] blocked.
// Staging: 256 thr x 16B coalesced global loads -> regs -> padded LDS
//   Kt rows 160B (80 u16), Vt rows 144B (72 u16): bank-uniform for all reads/writes.
// Next tile prefetched into regs during compute (loads pinned by sched_barrier).
// S^T trick (verified r5/r6): A=K rows pi0(l16)=(l16>>2)*8+(l16&3), pi0+4 ->
// lane (l16,q) holds P[qrow=l16][keys q*8..q*8+7] = PV B-frag; PV A=V^T -> O^T.
// No-max softmax (exp2 arg |max| ~25 << 127): l accumulated lane-locally.
__global__ __launch_bounds__(256) void k_flash(const u16* __restrict__ Qh, const u16* __restrict__ Kh,
                                               const u16* __restrict__ Vb, u16* __restrict__ o) {
    const float CEXP = 0.51006973f; // (8^-0.5) * log2(e)
    int qt = blockIdx.x, h = blockIdx.y, b = blockIdx.z;
    int tid = threadIdx.x;
    int wave = tid >> 6, lane = tid & 63, l16 = lane & 15, q = lane >> 4;

    __shared__ __align__(16) u16 Kt[64 * 80];   // [key][d], rows padded to 160B
    __shared__ __align__(16) u16 Vt[64 * 72];   // [d][key], rows padded to 144B

    int head = b * 8 + h;
    const u16* qp = Qh + ((size_t)head * 4096 + qt * 64 + wave * 16 + l16) * 64 + q * 8;
    short8 qf0 = *(const short8*)(qp);
    short8 qf1 = *(const short8*)(qp + 32);

    const u16* kb = Kh + (size_t)head * 4096 * 64;   // tile kt: +kt*4096 u16 (8KB contiguous)
    const u16* vb = Vb + (size_t)head * 4096 * 64;   // tile kt: +kt*4096 u16 (8KB contiguous)

    int idx0 = tid, idx1 = tid + 256;                // 16B-chunk ids within the 8KB tile
    int r0 = idx0 >> 3, g0 = idx0 & 7;               // row, 16B-granule
    int r1 = idx1 >> 3, g1 = idx1 & 7;

    f32x4 oacc[4];
#pragma unroll
    for (int c = 0; c < 4; ++c) oacc[c] = (f32x4){0.f, 0.f, 0.f, 0.f};
    float l_acc = 0.f;
    int pi0 = (l16 >> 2) * 8 + (l16 & 3);

    // prologue: tile 0 into regs (coalesced: 256 lanes x 16B contiguous)
    short8 rk0 = *(const short8*)(kb + idx0 * 8);
    short8 rk1 = *(const short8*)(kb + idx1 * 8);
    short8 rv0 = *(const short8*)(vb + idx0 * 8);
    short8 rv1 = *(const short8*)(vb + idx1 * 8);

#pragma unroll 1
    for (int kt = 0; kt < 64; ++kt) {
        __syncthreads();                              // prev tile's LDS reads done
        *(short8*)(&Kt[r0 * 80 + g0 * 8]) = rk0;
        *(short8*)(&Kt[r1 * 80 + g1 * 8]) = rk1;
        *(short8*)(&Vt[r0 * 72 + g0 * 8]) = rv0;
        *(short8*)(&Vt[r1 * 72 + g1 * 8]) = rv1;
        __syncthreads();                              // tile visible

        // prefetch next tile into regs (overlaps compute below; pinned here)
        int ktn = kt < 63 ? kt + 1 : 63;
        const u16* kbn = kb + (size_t)ktn * 4096;
        const u16* vbn = vb + (size_t)ktn * 4096;
        rk0 = *(const short8*)(kbn + idx0 * 8);
        rk1 = *(const short8*)(kbn + idx1 * 8);
        rv0 = *(const short8*)(vbn + idx0 * 8);
        rv1 = *(const short8*)(vbn + idx1 * 8);
        __builtin_amdgcn_sched_barrier(0);            // don't sink the prefetch into next iter

#pragma unroll
        for (int kk = 0; kk <= 32; kk += 32) {        // two 32-key sub-tiles
            short8 A00 = *(const short8*)(&Kt[(kk + pi0) * 80 + q * 8]);
            short8 A01 = *(const short8*)(&Kt[(kk + pi0) * 80 + q * 8 + 32]);
            short8 A10 = *(const short8*)(&Kt[(kk + pi0 + 4) * 80 + q * 8]);
            short8 A11 = *(const short8*)(&Kt[(kk + pi0 + 4) * 80 + q * 8 + 32]);
            f32x4 s0 = (f32x4){0.f, 0.f, 0.f, 0.f};
            f32x4 s1 = (f32x4){0.f, 0.f, 0.f, 0.f};
            s0 = mfma16(A00, qf0, s0); s0 = mfma16(A01, qf1, s0);  // S^T keys kk+q*8+r
            s1 = mfma16(A10, qf0, s1); s1 = mfma16(A11, qf1, s1);  // S^T keys kk+q*8+4+r

            short8 pf;
            float ls = 0.f;
#pragma unroll
            for (int r = 0; r < 4; ++r) {
                float p0 = exp2f(s0[r] * CEXP);
                float p1 = exp2f(s1[r] * CEXP);
                ls += p0 + p1;
                pf[r]     = (short)f2bf_up(p0);
                pf[4 + r] = (short)f2bf_up(p1);
            }
            l_acc += ls;
#pragma unroll
            for (int c = 0; c < 4; ++c) {
                short8 vfc = *(const short8*)(&Vt[(c * 16 + l16) * 72 + kk + q * 8]);
                oacc[c] = mfma16(vfc, pf, oacc[c]);   // O^T[d=c*16+q*4+r][qrow=l16]
            }
        }
    }

    l_acc += __shfl_xor(l_acc, 16);                   // sum the 4 quads of this qrow
    l_acc += __shfl_xor(l_acc, 32);
    float inv = 1.f / l_acc;

    u16* ob = o + (size_t)(b * T_SZ + qt * 64 + wave * 16 + l16) * 512 + h * 64 + q * 4;
#pragma unroll
    for (int c = 0; c < 4; ++c) {
        u16x4 w = { f2bf(oacc[c][0] * inv), f2bf(oacc[c][1] * inv),
                    f2bf(oacc[c][2] * inv), f2bf(oacc[c][3] * inv) };
        *(u16x4*)(ob + c * 16) = w;
    }
}

extern "C" void kernel_launch(void* const* d_in, const int* in_sizes, int n_in,
                              void* d_out, int out_size, void* d_ws, size_t ws_size,
                              hipStream_t stream) {
    const float* x    = (const float*)d_in[0];   // [2,4096,512] f32
    const float* cond = (const float*)d_in[1];   // [2,4096,512] f32
    const float* Wqk  = (const float*)d_in[2];   // [512,1024]   f32
    const float* Wv   = (const float*)d_in[3];   // [512,512]    f32
    const float* Wu   = (const float*)d_in[4];   // [512,512]    f32
    const float* bu   = (const float*)d_in[5];   // [512]        f32
    float* out = (float*)d_out;                  // [2,4096,512] f32

    const size_t MT = (size_t)B_SZ * T_SZ;       // 8192
    u16* xb    = (u16*)d_ws;                     // [8192,512]   8 MB
    u16* cb    = xb + MT * 512;                  // [8192,512]   8 MB
    u16* qh_ws = cb + MT * 512;                  // [16 heads,4096,64]  8 MB
    u16* kh_ws = qh_ws + MT * 512;               // [16 heads,4096,64]  8 MB
    u16* vb_ws = kh_ws + MT * 512;               // [16,64kt,64d,64k]   8 MB
    u16* at_ws = vb_ws + MT * 512;               // [8192,512]   8 MB
    u16* Wqk_t = at_ws + MT * 512;               // [1024,512]   1 MB
    u16* Wv_t  = Wqk_t + (size_t)1024 * 512;     // [512,512]  0.5 MB
    u16* Wu_t  = Wv_t + (size_t)512 * 512;       // [512,512]  0.5 MB

    k_cvt<<<(int)(MT * 512 / 1024), 256, 0, stream>>>(x, xb);
    k_cvt<<<(int)(MT * 512 / 1024), 256, 0, stream>>>(cond, cb);
    k_cvt_t<<<(512 * 1024) / 256, 256, 0, stream>>>(Wqk, Wqk_t, 512, 1024);
    k_cvt_t<<<(512 * 512) / 256, 256, 0, stream>>>(Wv, Wv_t, 512, 512);
    k_cvt_t<<<(512 * 512) / 256, 256, 0, stream>>>(Wu, Wu_t, 512, 512);

    k_gemm<u16, 1><<<dim3(128, 16), 256, 0, stream>>>(cb, Wqk_t, nullptr, qh_ws, kh_ws, 8192, 1024);
    k_gemm<u16, 2><<<dim3(8, 128), 256, 0, stream>>>(Wv_t, xb, nullptr, vb_ws, nullptr, 512, 8192);
    k_flash<<<dim3(64, 8, 2), 256, 0, stream>>>(qh_ws, kh_ws, vb_ws, at_ws);
    k_gemm<float, 0><<<dim3(128, 8), 256, 0, stream>>>(at_ws, Wu_t, bu, out, nullptr, 8192, 512);
}

// Round 8
// 261.477 us; speedup vs baseline: 2.7098x; 1.4506x over previous
//
#include <hip/hip_runtime.h>

#define B_SZ 2
#define T_SZ 4096

typedef unsigned short u16;
typedef __attribute__((ext_vector_type(8))) short short8;
typedef __attribute__((ext_vector_type(4))) float f32x4;
typedef __attribute__((ext_vector_type(4))) unsigned short u16x4;

#define CEXP 0.51006973f   // (8^-0.5) * log2(e), folded into Q projection

__device__ __forceinline__ u16 f2bf(float f) {            // round-to-nearest-even
    unsigned int u;
    __builtin_memcpy(&u, &f, 4);
    u = (u + 0x7fffu + ((u >> 16) & 1u)) >> 16;
    return (u16)u;
}
__device__ __forceinline__ u16 f2bf_up(float f) {         // round-half-up (p >= 0 only)
    unsigned int u;
    __builtin_memcpy(&u, &f, 4);
    return (u16)((u + 0x8000u) >> 16);
}
__device__ __forceinline__ f32x4 mfma16(short8 a, short8 b, f32x4 c) {
    return __builtin_amdgcn_mfma_f32_16x16x32_bf16(a, b, c, 0, 0, 0);
}

// ---------- f32 [K][N] -> bf16 [N][K] (convert + transpose, weights only) ----------
__global__ void k_cvt_t(const float* __restrict__ src, u16* __restrict__ dst, int K, int N) {
    int idx = blockIdx.x * 256 + threadIdx.x;
    int k = idx / N, n = idx - k * N;
    dst[(size_t)n * K + k] = f2bf(src[idx]);
}

// ---------- LDS-tiled GEMM: C[M,N] = A[M,512] x Bt[N,512]^T ----------
// 128x128 tile, 4 waves (64x64 quadrant each), BK=32, K=512 (16 iters).
// A/B staged through LDS (72-u16 padded rows: 16B-aligned, bank-conflict-free),
// coalesced 16B/lane staging with f32->bf16 convert fused when AF32/BF32.
// Reg prefetch of next K-slice pinned before compute via sched_barrier.
// MODE 0: C[row*N+col] (+bias), OutT store.
// MODE 1 (qk proj, N=1024): col<512 -> Qh[b,h,t,64] SCALED BY CEXP; else Kh at C2.
// MODE 2 (v proj, M=512, N=8192): row=ch, col=tok -> Vb[b,h,kt,64d,64k] blocked.
template <typename OutT, int MODE, bool AF32, bool BF32>
__global__ __launch_bounds__(256) void k_gemm2(const void* __restrict__ Ap, const void* __restrict__ Bp,
                                               const float* __restrict__ bias, OutT* __restrict__ C,
                                               OutT* __restrict__ C2, int M, int N) {
    const int K = 512;
    int m0 = blockIdx.x * 128, n0 = blockIdx.y * 128;
    int tid = threadIdx.x;
    int wave = tid >> 6, lane = tid & 63, l16 = lane & 15, q = lane >> 4;
    int mo = (wave & 1) * 64, no = (wave >> 1) * 64;

    __shared__ __align__(16) u16 As[128 * 72];
    __shared__ __align__(16) u16 Bs[128 * 72];

    f32x4 acc[4][4];
#pragma unroll
    for (int i = 0; i < 4; ++i)
#pragma unroll
        for (int j = 0; j < 4; ++j) acc[i][j] = (f32x4){0.f, 0.f, 0.f, 0.f};

    // staging registers
    float4 raf[4]; short8 rab[2];
    float4 rbf[4]; short8 rbb[2];

    const float* Af = (const float*)Ap; const u16* Ab = (const u16*)Ap;
    const float* Bf = (const float*)Bp; const u16* Bb = (const u16*)Bp;

    // prologue: K-slice 0
    if constexpr (AF32) {
#pragma unroll
        for (int jj = 0; jj < 4; ++jj) {
            int id = tid + 256 * jj, row = id >> 3, g = id & 7;      // 8 float4 per 32-f32 row
            raf[jj] = *(const float4*)(Af + (size_t)(m0 + row) * K + g * 4);
        }
    } else {
#pragma unroll
        for (int jj = 0; jj < 2; ++jj) {
            int id = tid + 256 * jj, row = id >> 2, g = id & 3;      // 4 granules per 32-u16 row
            rab[jj] = *(const short8*)(Ab + (size_t)(m0 + row) * K + g * 8);
        }
    }
    if constexpr (BF32) {
#pragma unroll
        for (int jj = 0; jj < 4; ++jj) {
            int id = tid + 256 * jj, row = id >> 3, g = id & 7;
            rbf[jj] = *(const float4*)(Bf + (size_t)(n0 + row) * K + g * 4);
        }
    } else {
#pragma unroll
        for (int jj = 0; jj < 2; ++jj) {
            int id = tid + 256 * jj, row = id >> 2, g = id & 3;
            rbb[jj] = *(const short8*)(Bb + (size_t)(n0 + row) * K + g * 8);
        }
    }

#pragma unroll 1
    for (int k0 = 0; k0 < K; k0 += 32) {
        __syncthreads();
        if constexpr (AF32) {
#pragma unroll
            for (int jj = 0; jj < 4; ++jj) {
                int id = tid + 256 * jj, row = id >> 3, g = id & 7;
                u16x4 w = { f2bf(raf[jj].x), f2bf(raf[jj].y), f2bf(raf[jj].z), f2bf(raf[jj].w) };
                *(u16x4*)(&As[row * 72 + g * 4]) = w;
            }
        } else {
#pragma unroll
            for (int jj = 0; jj < 2; ++jj) {
                int id = tid + 256 * jj, row = id >> 2, g = id & 3;
                *(short8*)(&As[row * 72 + g * 8]) = rab[jj];
            }
        }
        if constexpr (BF32) {
#pragma unroll
            for (int jj = 0; jj < 4; ++jj) {
                int id = tid + 256 * jj, row = id >> 3, g = id & 7;
                u16x4 w = { f2bf(rbf[jj].x), f2bf(rbf[jj].y), f2bf(rbf[jj].z), f2bf(rbf[jj].w) };
                *(u16x4*)(&Bs[row * 72 + g * 4]) = w;
            }
        } else {
#pragma unroll
            for (int jj = 0; jj < 2; ++jj) {
                int id = tid + 256 * jj, row = id >> 2, g = id & 3;
                *(short8*)(&Bs[row * 72 + g * 8]) = rbb[jj];
            }
        }
        __syncthreads();

        // prefetch next K-slice (last iter: harmless reload of same slice)
        int k1 = (k0 + 32 < K) ? k0 + 32 : k0;
        if constexpr (AF32) {
#pragma unroll
            for (int jj = 0; jj < 4; ++jj) {
                int id = tid + 256 * jj, row = id >> 3, g = id & 7;
                raf[jj] = *(const float4*)(Af + (size_t)(m0 + row) * K + k1 + g * 4);
            }
        } else {
#pragma unroll
            for (int jj = 0; jj < 2; ++jj) {
                int id = tid + 256 * jj, row = id >> 2, g = id & 3;
                rab[jj] = *(const short8*)(Ab + (size_t)(m0 + row) * K + k1 + g * 8);
            }
        }
        if constexpr (BF32) {
#pragma unroll
            for (int jj = 0; jj < 4; ++jj) {
                int id = tid + 256 * jj, row = id >> 3, g = id & 7;
                rbf[jj] = *(const float4*)(Bf + (size_t)(n0 + row) * K + k1 + g * 4);
            }
        } else {
#pragma unroll
            for (int jj = 0; jj < 2; ++jj) {
                int id = tid + 256 * jj, row = id >> 2, g = id & 3;
                rbb[jj] = *(const short8*)(Bb + (size_t)(n0 + row) * K + k1 + g * 8);
            }
        }
        __builtin_amdgcn_sched_barrier(0);

        short8 af[4], bf[4];
#pragma unroll
        for (int i = 0; i < 4; ++i) af[i] = *(const short8*)(&As[(mo + i * 16 + l16) * 72 + q * 8]);
#pragma unroll
        for (int j = 0; j < 4; ++j) bf[j] = *(const short8*)(&Bs[(no + j * 16 + l16) * 72 + q * 8]);
#pragma unroll
        for (int i = 0; i < 4; ++i)
#pragma unroll
            for (int j = 0; j < 4; ++j) acc[i][j] = mfma16(af[i], bf[j], acc[i][j]);
    }

    // epilogue: D row = q*4+r (m), col = l16 (n)
#pragma unroll
    for (int i = 0; i < 4; ++i)
#pragma unroll
        for (int j = 0; j < 4; ++j)
#pragma unroll
            for (int r = 0; r < 4; ++r) {
                int row = m0 + mo + i * 16 + q * 4 + r;
                int col = n0 + no + j * 16 + l16;
                float val = acc[i][j][r];
                if constexpr (MODE == 0) {
                    val += bias ? bias[col] : 0.f;
                    if constexpr (__is_same(OutT, float)) C[(size_t)row * N + col] = val;
                    else                                  C[(size_t)row * N + col] = f2bf(val);
                } else if constexpr (MODE == 1) {
                    int b = row >> 12, t = row & 4095, h = (col & 511) >> 6, d = col & 63;
                    size_t addr = ((size_t)((b * 8 + h) * 4096 + t)) * 64 + d;
                    if (col < 512) C[addr] = f2bf(val * CEXP);
                    else           C2[addr] = f2bf(val);
                } else { // MODE 2
                    int h = row >> 6, d = row & 63, b = col >> 12, t = col & 4095;
                    int kt = t >> 6, k64 = t & 63;
                    size_t addr = ((((size_t)(b * 8 + h) * 64 + kt) * 64 + d) << 6) + k64;
                    C[addr] = f2bf(val);
                }
            }
}

// ---------- flash attention: LDS-tiled + register S^T trick + MFMA l-sum ----------
// grid (T/64, H, B); block 256 = 4 waves; wave owns 16 q rows. 64-key LDS tiles.
// Qh (pre-scaled by CEXP)/Kh: [b,h,t,64]; Vb: [b,h,kt,64d,64k] blocked.
// S^T trick: A=K rows pi0(l16)=(l16>>2)*8+(l16&3), pi0+4 -> lane (l16,q) holds
// P[qrow=l16][keys q*8..q*8+7] = PV B-frag. PV: A=V^T -> O^T in regs.
// l computed by ones-A MFMA on the same P B-frags: every lane ends with the
// full l[qrow=l16] in lacc[.] -> no shuffles, no scalar adds in the loop.
__global__ __launch_bounds__(256) void k_flash(const u16* __restrict__ Qh, const u16* __restrict__ Kh,
                                               const u16* __restrict__ Vb, u16* __restrict__ o) {
    int qt = blockIdx.x, h = blockIdx.y, b = blockIdx.z;
    int tid = threadIdx.x;
    int wave = tid >> 6, lane = tid & 63, l16 = lane & 15, q = lane >> 4;

    __shared__ __align__(16) u16 Kt[64 * 80];   // [key][d], rows padded to 160B
    __shared__ __align__(16) u16 Vt[64 * 72];   // [d][key], rows padded to 144B

    int head = b * 8 + h;
    const u16* qp = Qh + ((size_t)head * 4096 + qt * 64 + wave * 16 + l16) * 64 + q * 8;
    short8 qf0 = *(const short8*)(qp);
    short8 qf1 = *(const short8*)(qp + 32);

    const u16* kb = Kh + (size_t)head * 4096 * 64;   // tile kt: +kt*4096 u16 (8KB contiguous)
    const u16* vb = Vb + (size_t)head * 4096 * 64;

    int idx0 = tid, idx1 = tid + 256;
    int r0 = idx0 >> 3, g0 = idx0 & 7;
    int r1 = idx1 >> 3, g1 = idx1 & 7;

    f32x4 oacc[4];
#pragma unroll
    for (int c = 0; c < 4; ++c) oacc[c] = (f32x4){0.f, 0.f, 0.f, 0.f};
    f32x4 lacc = (f32x4){0.f, 0.f, 0.f, 0.f};
    const short8 ones = { 0x3F80, 0x3F80, 0x3F80, 0x3F80, 0x3F80, 0x3F80, 0x3F80, 0x3F80 };
    int pi0 = (l16 >> 2) * 8 + (l16 & 3);

    short8 rk0 = *(const short8*)(kb + idx0 * 8);
    short8 rk1 = *(const short8*)(kb + idx1 * 8);
    short8 rv0 = *(const short8*)(vb + idx0 * 8);
    short8 rv1 = *(const short8*)(vb + idx1 * 8);

#pragma unroll 1
    for (int kt = 0; kt < 64; ++kt) {
        __syncthreads();
        *(short8*)(&Kt[r0 * 80 + g0 * 8]) = rk0;
        *(short8*)(&Kt[r1 * 80 + g1 * 8]) = rk1;
        *(short8*)(&Vt[r0 * 72 + g0 * 8]) = rv0;
        *(short8*)(&Vt[r1 * 72 + g1 * 8]) = rv1;
        __syncthreads();

        int ktn = kt < 63 ? kt + 1 : 63;
        const u16* kbn = kb + (size_t)ktn * 4096;
        const u16* vbn = vb + (size_t)ktn * 4096;
        rk0 = *(const short8*)(kbn + idx0 * 8);
        rk1 = *(const short8*)(kbn + idx1 * 8);
        rv0 = *(const short8*)(vbn + idx0 * 8);
        rv1 = *(const short8*)(vbn + idx1 * 8);
        __builtin_amdgcn_sched_barrier(0);

#pragma unroll
        for (int kk = 0; kk <= 32; kk += 32) {
            short8 A00 = *(const short8*)(&Kt[(kk + pi0) * 80 + q * 8]);
            short8 A01 = *(const short8*)(&Kt[(kk + pi0) * 80 + q * 8 + 32]);
            short8 A10 = *(const short8*)(&Kt[(kk + pi0 + 4) * 80 + q * 8]);
            short8 A11 = *(const short8*)(&Kt[(kk + pi0 + 4) * 80 + q * 8 + 32]);
            f32x4 s0 = (f32x4){0.f, 0.f, 0.f, 0.f};
            f32x4 s1 = (f32x4){0.f, 0.f, 0.f, 0.f};
            s0 = mfma16(A00, qf0, s0); s0 = mfma16(A01, qf1, s0);  // S^T keys kk+q*8+r
            s1 = mfma16(A10, qf0, s1); s1 = mfma16(A11, qf1, s1);  // S^T keys kk+q*8+4+r

            short8 pf;
#pragma unroll
            for (int r = 0; r < 4; ++r) {
                pf[r]     = (short)f2bf_up(exp2f(s0[r]));
                pf[4 + r] = (short)f2bf_up(exp2f(s1[r]));
            }
            lacc = mfma16(ones, pf, lacc);            // l[qrow=l16] += sum of this 32-key P slab
#pragma unroll
            for (int c = 0; c < 4; ++c) {
                short8 vfc = *(const short8*)(&Vt[(c * 16 + l16) * 72 + kk + q * 8]);
                oacc[c] = mfma16(vfc, pf, oacc[c]);   // O^T[d=c*16+q*4+r][qrow=l16]
            }
        }
    }

    float inv = 1.f / lacc[0];                        // every lane holds full l[qrow=l16]

    u16* ob = o + (size_t)(b * T_SZ + qt * 64 + wave * 16 + l16) * 512 + h * 64 + q * 4;
#pragma unroll
    for (int c = 0; c < 4; ++c) {
        u16x4 w = { f2bf(oacc[c][0] * inv), f2bf(oacc[c][1] * inv),
                    f2bf(oacc[c][2] * inv), f2bf(oacc[c][3] * inv) };
        *(u16x4*)(ob + c * 16) = w;
    }
}

extern "C" void kernel_launch(void* const* d_in, const int* in_sizes, int n_in,
                              void* d_out, int out_size, void* d_ws, size_t ws_size,
                              hipStream_t stream) {
    const float* x    = (const float*)d_in[0];   // [2,4096,512] f32
    const float* cond = (const float*)d_in[1];   // [2,4096,512] f32
    const float* Wqk  = (const float*)d_in[2];   // [512,1024]   f32
    const float* Wv   = (const float*)d_in[3];   // [512,512]    f32
    const float* Wu   = (const float*)d_in[4];   // [512,512]    f32
    const float* bu   = (const float*)d_in[5];   // [512]        f32
    float* out = (float*)d_out;                  // [2,4096,512] f32

    const size_t MT = (size_t)B_SZ * T_SZ;       // 8192
    u16* qh_ws = (u16*)d_ws;                     // [16 heads,4096,64]  8 MB (Q pre-scaled)
    u16* kh_ws = qh_ws + MT * 512;               // [16 heads,4096,64]  8 MB
    u16* vb_ws = kh_ws + MT * 512;               // [16,64kt,64d,64k]   8 MB
    u16* at_ws = vb_ws + MT * 512;               // [8192,512]          8 MB
    u16* Wqk_t = at_ws + MT * 512;               // [1024,512]          1 MB
    u16* Wv_t  = Wqk_t + (size_t)1024 * 512;     // [512,512]         0.5 MB
    u16* Wu_t  = Wv_t + (size_t)512 * 512;       // [512,512]         0.5 MB

    k_cvt_t<<<(512 * 1024) / 256, 256, 0, stream>>>(Wqk, Wqk_t, 512, 1024);
    k_cvt_t<<<(512 * 512) / 256, 256, 0, stream>>>(Wv, Wv_t, 512, 512);
    k_cvt_t<<<(512 * 512) / 256, 256, 0, stream>>>(Wu, Wu_t, 512, 512);

    // qk proj: A=cond (f32, convert-on-stage), B=Wqk_t -> Qh(scaled)/Kh
    k_gemm2<u16, 1, true, false><<<dim3(64, 8), 256, 0, stream>>>(cond, Wqk_t, nullptr, qh_ws, kh_ws, 8192, 1024);
    // v proj (transposed): A=Wv_t, B=x (f32, convert-on-stage) -> Vb blocked
    k_gemm2<u16, 2, false, true><<<dim3(4, 64), 256, 0, stream>>>(Wv_t, x, nullptr, vb_ws, nullptr, 512, 8192);
    k_flash<<<dim3(64, 8, 2), 256, 0, stream>>>(qh_ws, kh_ws, vb_ws, at_ws);
    // out proj: A=at, B=Wu_t, +bias -> f32 out
    k_gemm2<float, 0, false, false><<<dim3(64, 4), 256, 0, stream>>>(at_ws, Wu_t, bu, out, nullptr, 8192, 512);
}